// Round 5
// baseline (9.842 us; speedup 1.0000x reference)
//
#include <hip/hip_runtime.h>
#include <hip/hip_bf16.h>

// out[l,m,p,o] = sum_{k,j,i} w[k,j,l,m,i] * s[2*(l+k-1)+j, p, (o+i-2) mod 56]
//   s[c,p,q] = x[c,p,q] + x[c+64,p,q]
//   contribution valid iff 0 <= l+k-1 < 32 and 0 <= o+i-1 < 56
// final[l*4+m, (p+1)%56, o] = out[l,m,p,o]
//
// Direct-load version: no LDS, no shuffles, no barriers. Each lane loads the
// 3 columns it needs per channel (wrap stays inside the row -> always a valid
// address). Out-of-range l+k-1 is handled by clamping the ADDRESS (scalar)
// and zeroing the WEIGHT (scalar cselect) so all 36 loads issue unconditionally
// in one batch. 3 accumulators shorten the FMA dependency chain.
__global__ __launch_bounds__(256) void fused_unfold_einsum(
    const float* __restrict__ x,   // (128, 56, 56)
    const float* __restrict__ w,   // (3, 2, 32, 4, 3)
    float* __restrict__ out)       // (128, 56, 56)
{
    const int pg = blockIdx.x;          // 0..13
    const int lm = blockIdx.y;          // 0..127
    const int l  = lm >> 2;             // 0..31 (uniform)
    const int m  = lm & 3;              // 0..3  (uniform)
    const int tid  = threadIdx.x;
    const int lane = tid & 63;
    const int po   = tid >> 6;          // 0..3 (wave-uniform)
    const int p    = pg * 4 + po;       // 0..55

    const int o  = (lane < 56) ? lane : 55;   // dup lanes 56..63, masked at store

    // source columns with the q-roll folded in (all are valid addresses):
    const int q2 = o;                          // i=2 (valid o <= 54)
    const int q1 = (o == 0) ? 55 : o - 1;      // i=1 (always valid; o==0 wraps)
    const int q0 = (o >= 2) ? o - 2 : 55;      // i=0 (valid o >= 1; o==1 wraps)
    const bool v0ok = (o >= 1);
    const bool v2ok = (o <= 54);

    float acc0 = 0.f, acc1 = 0.f, acc2 = 0.f;

    #pragma unroll
    for (int ch = 0; ch < 6; ++ch) {
        const int kk = ch >> 1;
        int lsrc = l - 1 + kk;                       // uniform
        const bool chok = ((unsigned)lsrc < 32u);    // uniform
        lsrc = chok ? lsrc : 0;                      // clamp address only

        const float* __restrict__ r0 = x + (2 * lsrc + (ch & 1)) * 3136 + p * 56;
        const float* __restrict__ r1 = r0 + 64 * 3136;

        float v0 = r0[q0] + r1[q0];
        float v1 = r0[q1] + r1[q1];
        float v2 = r0[q2] + r1[q2];
        if (!v0ok) v0 = 0.f;
        if (!v2ok) v2 = 0.f;

        // w[k,j,l,m,i] at ((ch)*32 + l)*12 + m*3 + i  (uniform -> s_load)
        const float* wp = w + (ch * 32 + l) * 12 + m * 3;
        const float w0 = chok ? wp[0] : 0.f;         // scalar cselect
        const float w1 = chok ? wp[1] : 0.f;
        const float w2 = chok ? wp[2] : 0.f;

        acc0 = fmaf(w0, v0, acc0);
        acc1 = fmaf(w1, v1, acc1);
        acc2 = fmaf(w2, v2, acc2);
    }

    if (lane < 56) {
        const int p_out = (p + 1 == 56) ? 0 : (p + 1);
        out[((l * 4 + m) * 56 + p_out) * 56 + lane] = acc0 + acc1 + acc2;
    }
}

extern "C" void kernel_launch(void* const* d_in, const int* in_sizes, int n_in,
                              void* d_out, int out_size, void* d_ws, size_t ws_size,
                              hipStream_t stream) {
    const float* x = (const float*)d_in[0];
    const float* w = (const float*)d_in[1];
    float* out = (float*)d_out;

    dim3 grid(14, 128);   // (p-groups, l*4+m) -> 7168 waves (28/CU)
    dim3 block(256);      // 4 waves; wave = one p-row, lane = o column
    fused_unfold_einsum<<<grid, block, 0, stream>>>(x, w, out);
}

// Round 6
// 9.650 us; speedup vs baseline: 1.0200x; 1.0200x over previous
//
#include <hip/hip_runtime.h>
#include <hip/hip_bf16.h>

// out[l,m,p,o] = sum_{k,j,i} w[k,j,l,m,i] * s[2*(l+k-1)+j, p, (o+i-2) mod 56]
//   s[c,p,q] = x[c,p,q] + x[c+64,p,q]
//   contribution valid iff 0 <= l+k-1 < 32 and 0 <= o+i-1 < 56
// final[l*4+m, (p+1)%56, o] = out[l,m,p,o]
//
// R6: identical per-thread body to R5 (direct loads, no LDS/barriers); the ONLY
// change is block geometry: 512-thread blocks (8 waves) -> 896 workgroups
// instead of 1792, isolating workgroup-dispatch overhead from wave exec.
__global__ __launch_bounds__(512) void fused_unfold_einsum(
    const float* __restrict__ x,   // (128, 56, 56)
    const float* __restrict__ w,   // (3, 2, 32, 4, 3)
    float* __restrict__ out)       // (128, 56, 56)
{
    const int pg = blockIdx.x;          // 0..6  (8 p-rows per block)
    const int lm = blockIdx.y;          // 0..127
    const int l  = lm >> 2;             // 0..31 (uniform)
    const int m  = lm & 3;              // 0..3  (uniform)
    const int tid  = threadIdx.x;
    const int lane = tid & 63;
    const int po   = tid >> 6;          // 0..7 (wave-uniform)
    const int p    = pg * 8 + po;       // 0..55

    const int o  = (lane < 56) ? lane : 55;   // dup lanes 56..63, masked at store

    // source columns with the q-roll folded in (all are valid addresses):
    const int q2 = o;                          // i=2 (valid o <= 54)
    const int q1 = (o == 0) ? 55 : o - 1;      // i=1 (always valid; o==0 wraps)
    const int q0 = (o >= 2) ? o - 2 : 55;      // i=0 (valid o >= 1; o==1 wraps)
    const bool v0ok = (o >= 1);
    const bool v2ok = (o <= 54);

    float acc0 = 0.f, acc1 = 0.f, acc2 = 0.f;

    #pragma unroll
    for (int ch = 0; ch < 6; ++ch) {
        const int kk = ch >> 1;
        int lsrc = l - 1 + kk;                       // uniform
        const bool chok = ((unsigned)lsrc < 32u);    // uniform
        lsrc = chok ? lsrc : 0;                      // clamp address only

        const float* __restrict__ r0 = x + (2 * lsrc + (ch & 1)) * 3136 + p * 56;
        const float* __restrict__ r1 = r0 + 64 * 3136;

        float v0 = r0[q0] + r1[q0];
        float v1 = r0[q1] + r1[q1];
        float v2 = r0[q2] + r1[q2];
        if (!v0ok) v0 = 0.f;
        if (!v2ok) v2 = 0.f;

        // w[k,j,l,m,i] at ((ch)*32 + l)*12 + m*3 + i  (uniform -> s_load)
        const float* wp = w + (ch * 32 + l) * 12 + m * 3;
        const float w0 = chok ? wp[0] : 0.f;         // scalar cselect
        const float w1 = chok ? wp[1] : 0.f;
        const float w2 = chok ? wp[2] : 0.f;

        acc0 = fmaf(w0, v0, acc0);
        acc1 = fmaf(w1, v1, acc1);
        acc2 = fmaf(w2, v2, acc2);
    }

    if (lane < 56) {
        const int p_out = (p + 1 == 56) ? 0 : (p + 1);
        out[((l * 4 + m) * 56 + p_out) * 56 + lane] = acc0 + acc1 + acc2;
    }
}

extern "C" void kernel_launch(void* const* d_in, const int* in_sizes, int n_in,
                              void* d_out, int out_size, void* d_ws, size_t ws_size,
                              hipStream_t stream) {
    const float* x = (const float*)d_in[0];
    const float* w = (const float*)d_in[1];
    float* out = (float*)d_out;

    dim3 grid(7, 128);    // (p-groups of 8, l*4+m) -> 896 workgroups, 7168 waves
    dim3 block(512);      // 8 waves; wave = one p-row, lane = o column
    fused_unfold_einsum<<<grid, block, 0, stream>>>(x, w, out);
}